// Round 4
// baseline (91.378 us; speedup 1.0000x reference)
//
#include <hip/hip_runtime.h>

// Correlation layer, specialized: s1=2, s2=1, d=4 -> integer even sampling,
// bilinear weights exactly 0 -> pure gather:
// out[b, j*9+i, h1, w1] = (1/256) * sum_c x1[b,c,2h1,2w1] * x2[b,c,2(h1+j-4),2(w1+i-4)]
// (zero when displaced downsampled position is outside the 24x24 grid)
//
// Fused split-C: 8 cz-blocks per spatial tile write partials to ws; the LAST
// arriving block (device-scope atomic counter) sums them and writes d_out.
// Deterministic: fixed cz summation order, exactly one reducer per tile.

constexpr int NB = 16, NC = 256, NH = 48, NW = 48;
constexpr int H1 = 24, W1 = 24, NK = 81, HW = NH * NW;
constexpr int CSPLIT = 8, CPB = 32, CCH = 16;  // 8 blocks x 32 ch, staged 16/chunk
constexpr int TH = 4;                           // 6 h-tiles
constexpr int NTILE = (H1 / TH) * NB;           // 96 spatial tiles
constexpr int PPT = TH * W1 * NK;               // 7776 partial floats per (tile,cz)
constexpr int OUTSZ = NB * NK * H1 * W1;        // 746496

// MODE 0: fused partial+last-block-reduce via ws. MODE 1: atomicAdd fallback.
template<int MODE>
__global__ __launch_bounds__(256, 4) void corr_fused(
    const float* __restrict__ x1, const float* __restrict__ x2,
    float* __restrict__ out, float* __restrict__ part, int* __restrict__ counters)
{
  const int t   = threadIdx.x;
  const int h1t = blockIdx.x;   // 0..5
  const int b   = blockIdx.y;   // 0..15
  const int cz  = blockIdx.z;   // 0..7
  const int h1base = h1t * TH;

  __shared__ float s1[CCH][TH][24];      // 6 KB
  __shared__ float s2[CCH][TH + 8][36];  // 27.6 KB (32 data cols + pad)
  __shared__ int sLast;

  const int h1l = t / 54;       // compute decomposition (h1l 4, j 9, wg 6) = 216
  const int rr  = t % 54;
  const int j   = rr / 6;
  const int wg  = rr % 6;

  float acc[9][4];
  #pragma unroll
  for (int i = 0; i < 9; ++i) { acc[i][0]=0.f; acc[i][1]=0.f; acc[i][2]=0.f; acc[i][3]=0.f; }

  for (int ch = 0; ch < CPB; ch += CCH) {
    const int cb = cz * CPB + ch;
    if (ch) __syncthreads();    // protect LDS from previous chunk's readers

    // stage x2: 16c x 12rows x 32cols; float4 slots (keep .x,.z): 3072 = 256x12
    const float* p2 = x2 + (size_t)(b * NC + cb) * HW;
    #pragma unroll
    for (int q = 0; q < 12; ++q) {
      const int idx = t + q * 256;
      const int xh = idx & 15;           // cols 2xh-4, 2xh-3 (downsampled)
      const int r  = (idx >> 4) % 12;
      const int c  = idx / 192;
      const int ys = h1base - 4 + r;
      float vx = 0.f, vz = 0.f;
      if (ys >= 0 && ys < H1 && xh >= 2 && xh <= 13) {
        const float4 v = *(const float4*)&p2[(size_t)c * HW + (size_t)(2 * ys) * NW + (4 * xh - 8)];
        vx = v.x; vz = v.z;
      }
      s2[c][r][2 * xh]     = vx;
      s2[c][r][2 * xh + 1] = vz;
    }
    // stage x1: 16c x 4h x 24w; float4 slots: 768 = 256x3
    const float* p1 = x1 + (size_t)(b * NC + cb) * HW;
    #pragma unroll
    for (int q = 0; q < 3; ++q) {
      const int idx = t + q * 256;
      const int xq = idx % 12;
      const int hh = (idx / 12) & 3;
      const int c  = idx / 48;
      const float4 v = *(const float4*)&p1[(size_t)c * HW
                          + (size_t)(2 * (h1base + hh)) * NW + 4 * xq];
      s1[c][hh][2 * xq]     = v.x;
      s1[c][hh][2 * xq + 1] = v.z;
    }
    __syncthreads();

    if (t < 216) {
      #pragma unroll 4
      for (int c = 0; c < CCH; ++c) {
        const float4 a4 = *(const float4*)&s1[c][h1l][wg * 4];
        const float* xr = &s2[c][h1l + j][wg * 4];
        const float4 b0 = *(const float4*)&xr[0];
        const float4 b1 = *(const float4*)&xr[4];
        const float4 b2 = *(const float4*)&xr[8];
        const float av[4]  = {a4.x, a4.y, a4.z, a4.w};
        const float xw[12] = {b0.x, b0.y, b0.z, b0.w, b1.x, b1.y, b1.z, b1.w,
                              b2.x, b2.y, b2.z, b2.w};
        #pragma unroll
        for (int i = 0; i < 9; ++i)
          #pragma unroll
          for (int w = 0; w < 4; ++w)
            acc[i][w] = fmaf(av[w], xw[w + i], acc[i][w]);
      }
    }
  }

  if (MODE == 1) {
    if (t < 216) {
      const int h1 = h1base + h1l;
      const int w1 = wg * 4;
      #pragma unroll
      for (int i = 0; i < 9; ++i) {
        const int k = j * 9 + i;
        #pragma unroll
        for (int w = 0; w < 4; ++w)
          atomicAdd(&out[((size_t)(b * NK + k) * H1 + h1) * W1 + w1 + w],
                    acc[i][w] * (1.f / 256.f));
      }
    }
    return;
  }

  // ---- write block-linear partial: thread owns 144B contiguous ----
  const int tile = h1t * NB + b;
  if (t < 216) {
    float* pb = part + ((size_t)tile * CSPLIT + cz) * PPT + (size_t)t * 36;
    #pragma unroll
    for (int i = 0; i < 9; ++i)
      *(float4*)&pb[i * 4] = make_float4(acc[i][0], acc[i][1], acc[i][2], acc[i][3]);
  }
  __syncthreads();                    // all stores issued (drained at barrier)
  if (t == 0) {
    __threadfence();                  // release: partials device-visible
    sLast = (atomicAdd(&counters[tile], 1) == CSPLIT - 1);
  }
  __syncthreads();
  if (!sLast) return;

  // ---- last block of this tile: reduce 8 partials, write output ----
  __threadfence();                    // acquire: see siblings' partials
  const float* tp_ = part + (size_t)tile * CSPLIT * PPT;
  const float sc = 1.f / (float)NC;
  for (int n = t; n < PPT / 4; n += 256) {    // 1944 float4s
    float4 s = make_float4(0.f, 0.f, 0.f, 0.f);
    #pragma unroll
    for (int z = 0; z < CSPLIT; ++z) {
      const float4 v = *(const float4*)&tp_[(size_t)z * PPT + n * 4];
      s.x += v.x; s.y += v.y; s.z += v.z; s.w += v.w;
    }
    s.x *= sc; s.y *= sc; s.z *= sc; s.w *= sc;
    const int i   = n % 9;
    const int tp2 = n / 9;
    const int hl  = tp2 / 54;
    const int r2  = tp2 % 54;
    const int j2  = r2 / 6;
    const int wg2 = r2 % 6;
    const int k   = j2 * 9 + i;
    *(float4*)&out[(((size_t)b * NK + k) * H1 + (h1base + hl)) * W1 + wg2 * 4] = s;
  }
}

extern "C" void kernel_launch(void* const* d_in, const int* in_sizes, int n_in,
                              void* d_out, int out_size, void* d_ws, size_t ws_size,
                              hipStream_t stream) {
  const float* x1 = (const float*)d_in[0];
  const float* x2 = (const float*)d_in[1];
  float* out = (float*)d_out;

  const size_t partBytes = (size_t)NTILE * CSPLIT * PPT * sizeof(float);  // ~23.9 MB
  const size_t need = partBytes + NTILE * sizeof(int);
  const dim3 grid(H1 / TH, NB, CSPLIT);   // (6, 16, 8) = 768 blocks

  if (ws_size >= need) {
    float* part = (float*)d_ws;
    int* counters = (int*)((char*)d_ws + partBytes);
    hipMemsetAsync(counters, 0, NTILE * sizeof(int), stream);
    corr_fused<0><<<grid, 256, 0, stream>>>(x1, x2, out, part, counters);
  } else {
    hipMemsetAsync(d_out, 0, (size_t)OUTSZ * sizeof(float), stream);
    corr_fused<1><<<grid, 256, 0, stream>>>(x1, x2, out, nullptr, nullptr);
  }
}

// Round 5
// 36.745 us; speedup vs baseline: 2.4868x; 2.4868x over previous
//
#include <hip/hip_runtime.h>

// Correlation layer, specialized: s1=2, s2=1, d=4 -> integer even sampling,
// bilinear weights exactly 0 -> pure gather:
// out[b, j*9+i, h1, w1] = (1/256) * sum_c x1[b,c,2h1,2w1] * x2[b,c,2(h1+j-4),2(w1+i-4)]
// (zero when displaced downsampled position is outside the 24x24 grid)

constexpr int NB = 16, NC = 256, NH = 48, NW = 48;
constexpr int H1 = 24, W1 = 24, NK = 81, HW = NH * NW;
constexpr int CSPLIT = 16, CPB = 16;        // 16 channels per block, single chunk
constexpr int TH = 4;                        // h1 rows per block -> h1t in 0..5
constexpr int NTILE = (H1 / TH) * NB;        // 96 spatial tiles
constexpr int NT = 216;                      // active compute threads (4h x 9j x 6wg)
constexpr int PPT4 = 9 * NT;                 // 1944 float4 partials per (tile,cz)
constexpr int OUTSZ = NB * NK * H1 * W1;     // 746496

// MODE 0: transposed block-linear partials in ws + coalesced reduce kernel
// MODE 1: atomicAdd fallback if ws too small
template<int MODE>
__global__ __launch_bounds__(256, 4) void corr_main(
    const float* __restrict__ x1, const float* __restrict__ x2,
    float* __restrict__ dst)
{
  const int t   = threadIdx.x;
  const int h1t = blockIdx.x;   // 0..5
  const int b   = blockIdx.y;   // 0..15
  const int cz  = blockIdx.z;   // 0..15
  const int h1base = h1t * TH;
  const int cb = cz * CPB;

  __shared__ float s1[CPB][TH][24];   // 6 KB    x1 downsampled tile
  __shared__ float s2[CPB][12][36];   // 27.6 KB x2 downsampled window (32 cols + pad)

  // ---- phase 1: issue ALL global loads into registers (15-deep MLP) ----
  // x2: c(16) x r(12) x xh(16) float4 slots = 3072 = 256 x 12
  float4 r2[12];
  int w2c[12], w2r[12], w2x[12];
  {
    const float* p2 = x2 + (size_t)(b * NC + cb) * HW;
    #pragma unroll
    for (int q = 0; q < 12; ++q) {
      const int idx = t + q * 256;       // = 192c + 16r + xh
      const int xh = idx & 15;
      const int r  = (idx >> 4) % 12;
      const int c  = idx / 192;
      const int ys = h1base - 4 + r;
      w2c[q] = c; w2r[q] = r; w2x[q] = xh;
      r2[q] = make_float4(0.f, 0.f, 0.f, 0.f);
      if (ys >= 0 && ys < H1 && xh >= 2 && xh <= 13)
        r2[q] = *(const float4*)&p2[(size_t)c * HW + (size_t)(2 * ys) * NW + (4 * xh - 8)];
    }
  }
  // x1: c(16) x h(4) x xq(12) float4 slots = 768 = 256 x 3
  float4 r1[3];
  int w1c[3], w1h[3], w1x[3];
  {
    const float* p1 = x1 + (size_t)(b * NC + cb) * HW;
    #pragma unroll
    for (int q = 0; q < 3; ++q) {
      const int idx = t + q * 256;       // = 48c + 12h + xq
      const int xq = idx % 12;
      const int hh = (idx / 12) & 3;
      const int c  = idx / 48;
      w1c[q] = c; w1h[q] = hh; w1x[q] = xq;
      r1[q] = *(const float4*)&p1[(size_t)c * HW + (size_t)(2 * (h1base + hh)) * NW + 4 * xq];
    }
  }
  // ---- phase 2: LDS writes (keep .x,.z of each stride-2 float4) ----
  #pragma unroll
  for (int q = 0; q < 12; ++q) {
    s2[w2c[q]][w2r[q]][2 * w2x[q]]     = r2[q].x;
    s2[w2c[q]][w2r[q]][2 * w2x[q] + 1] = r2[q].z;
  }
  #pragma unroll
  for (int q = 0; q < 3; ++q) {
    s1[w1c[q]][w1h[q]][2 * w1x[q]]     = r1[q].x;
    s1[w1c[q]][w1h[q]][2 * w1x[q] + 1] = r1[q].z;
  }
  __syncthreads();

  // ---- phase 3: compute (h1l 4) x (j 9) x (wg 6) = 216 active of 256 ----
  if (t >= NT) return;
  const int h1l = t / 54;
  const int rr  = t % 54;
  const int j   = rr / 6;
  const int wg  = rr % 6;

  float acc[9][4];
  #pragma unroll
  for (int i = 0; i < 9; ++i) { acc[i][0]=0.f; acc[i][1]=0.f; acc[i][2]=0.f; acc[i][3]=0.f; }

  #pragma unroll 4
  for (int c = 0; c < CPB; ++c) {
    const float4 a4 = *(const float4*)&s1[c][h1l][wg * 4];
    const float* xr = &s2[c][h1l + j][wg * 4];
    const float4 b0 = *(const float4*)&xr[0];
    const float4 b1 = *(const float4*)&xr[4];
    const float4 b2 = *(const float4*)&xr[8];
    const float av[4]  = {a4.x, a4.y, a4.z, a4.w};
    const float xw[12] = {b0.x, b0.y, b0.z, b0.w, b1.x, b1.y, b1.z, b1.w,
                          b2.x, b2.y, b2.z, b2.w};
    #pragma unroll
    for (int i = 0; i < 9; ++i)
      #pragma unroll
      for (int w = 0; w < 4; ++w)
        acc[i][w] = fmaf(av[w], xw[w + i], acc[i][w]);
  }

  if (MODE == 0) {
    // transposed partial layout: float4 index = tileBase + i*216 + t
    // -> each wave store instruction covers 1 KB contiguous (full lines)
    const int tile = h1t * NB + b;
    float4* pb = (float4*)dst + ((size_t)cz * NTILE + tile) * PPT4;
    #pragma unroll
    for (int i = 0; i < 9; ++i)
      pb[i * NT + t] = make_float4(acc[i][0], acc[i][1], acc[i][2], acc[i][3]);
  } else {
    const int h1 = h1base + h1l;
    const int w1 = wg * 4;
    #pragma unroll
    for (int i = 0; i < 9; ++i) {
      const int k = j * 9 + i;
      #pragma unroll
      for (int w = 0; w < 4; ++w)
        atomicAdd(&dst[((size_t)(b * NK + k) * H1 + h1) * W1 + w1 + w],
                  acc[i][w] * (1.f / 256.f));
    }
  }
}

// Coalesced reduce: consecutive threads read consecutive partial float4s.
__global__ __launch_bounds__(256) void corr_reduce(const float* __restrict__ part,
                                                   float* __restrict__ out)
{
  const int n = blockIdx.x * 256 + threadIdx.x;   // 0 .. 186623
  if (n >= OUTSZ / 4) return;
  const int tp   = n % NT;          // producer thread id
  const int i    = (n / NT) % 9;    // displacement col index
  const int tile = n / PPT4;        // h1t*16 + b
  const int b    = tile % NB;
  const int h1t  = tile / NB;

  const float4* p4 = (const float4*)part;
  const size_t inner = (size_t)tile * PPT4 + i * NT + tp;
  float4 s = make_float4(0.f, 0.f, 0.f, 0.f);
  #pragma unroll
  for (int cz = 0; cz < CSPLIT; ++cz) {
    const float4 v = p4[(size_t)cz * NTILE * PPT4 + inner];
    s.x += v.x; s.y += v.y; s.z += v.z; s.w += v.w;
  }
  const float sc = 1.f / (float)NC;
  const int h1l = tp / 54;
  const int rr  = tp % 54;
  const int j   = rr / 6;
  const int wg  = rr % 6;
  const int k   = j * 9 + i;
  const int h1  = h1t * TH + h1l;
  *(float4*)&out[(((size_t)b * NK + k) * H1 + h1) * W1 + wg * 4] =
      make_float4(s.x * sc, s.y * sc, s.z * sc, s.w * sc);
}

extern "C" void kernel_launch(void* const* d_in, const int* in_sizes, int n_in,
                              void* d_out, int out_size, void* d_ws, size_t ws_size,
                              hipStream_t stream) {
  const float* x1 = (const float*)d_in[0];
  const float* x2 = (const float*)d_in[1];
  float* out = (float*)d_out;

  const size_t need = (size_t)CSPLIT * NTILE * PPT4 * 16;  // ~47.8 MB
  const dim3 grid(H1 / TH, NB, CSPLIT);   // (6, 16, 16) = 1536 blocks
  if (ws_size >= need) {
    float* part = (float*)d_ws;
    corr_main<0><<<grid, 256, 0, stream>>>(x1, x2, part);
    corr_reduce<<<(OUTSZ / 4 + 255) / 256, 256, 0, stream>>>(part, out);
  } else {
    hipMemsetAsync(d_out, 0, (size_t)OUTSZ * sizeof(float), stream);
    corr_main<1><<<grid, 256, 0, stream>>>(x1, x2, out);
  }
}

// Round 6
// 26.779 us; speedup vs baseline: 3.4123x; 1.3722x over previous
//
#include <hip/hip_runtime.h>
#include <hip/hip_fp16.h>

// Correlation layer, specialized: s1=2, s2=1, d=4 -> integer even sampling,
// bilinear weights exactly 0 -> pure gather:
// out[b, j*9+i, h1, w1] = (1/256) * sum_c x1[b,c,2h1,2w1] * x2[b,c,2(h1+j-4),2(w1+i-4)]
// (zero when displaced downsampled position is outside the 24x24 grid)

constexpr int NB = 16, NC = 256, NH = 48, NW = 48;
constexpr int H1 = 24, W1 = 24, NK = 81, HW = NH * NW;
constexpr int CSPLIT = 8, CPB = 32, CCH = 16;  // 8 blocks x 32ch, staged 16/chunk
constexpr int TH = 4;                           // h1 rows per block -> h1t 0..5
constexpr int NTILE = (H1 / TH) * NB;           // 96 spatial tiles
constexpr int NT = 216;                         // compute threads (4h x 9j x 6wg)
constexpr int PPT = 9 * NT;                     // 1944 Half4 per (tile,cz)
constexpr int OUTSZ = NB * NK * H1 * W1;        // 746496

struct alignas(8) Half4 { __half2 lo, hi; };

// MODE 0: fp16 transposed partials in ws + coalesced reduce kernel
// MODE 1: atomicAdd fallback if ws too small
template<int MODE>
__global__ __launch_bounds__(256, 4) void corr_main(
    const float* __restrict__ x1, const float* __restrict__ x2,
    void* __restrict__ dst)
{
  const int t   = threadIdx.x;
  const int h1t = blockIdx.x;   // 0..5
  const int b   = blockIdx.y;   // 0..15
  const int cz  = blockIdx.z;   // 0..7
  const int h1base = h1t * TH;

  __shared__ float s1[CCH][TH][24];   // 6 KB
  __shared__ float s2[CCH][12][36];   // 27.6 KB (32 data cols + pad)

  const int h1l = t / 54;             // compute decomposition: 216 active
  const int rr  = t % 54;
  const int j   = rr / 6;
  const int wg  = rr % 6;

  const float* base1 = x1 + (size_t)(b * NC + cz * CPB) * HW;
  const float* base2 = x2 + (size_t)(b * NC + cz * CPB) * HW;

  float4 R2[12], R1[3];               // staging registers, reused across chunks

  auto loads = [&](int chunk) {
    const float* p2 = base2 + (size_t)chunk * CCH * HW;
    #pragma unroll
    for (int q = 0; q < 12; ++q) {
      const int idx = t + q * 256;    // xh(16) r(12) c(16)
      const int xh = idx & 15;
      const int r  = (idx >> 4) % 12;
      const int c  = idx / 192;
      const int ys = h1base - 4 + r;
      R2[q] = make_float4(0.f, 0.f, 0.f, 0.f);
      if (ys >= 0 && ys < H1 && xh >= 2 && xh <= 13)
        R2[q] = *(const float4*)&p2[(size_t)c * HW + (size_t)(2 * ys) * NW + (4 * xh - 8)];
    }
    const float* p1 = base1 + (size_t)chunk * CCH * HW;
    #pragma unroll
    for (int q = 0; q < 3; ++q) {
      const int idx = t + q * 256;    // xq(12) hh(4) c(16)
      const int xq = idx % 12;
      const int hh = (idx / 12) & 3;
      const int c  = idx / 48;
      R1[q] = *(const float4*)&p1[(size_t)c * HW + (size_t)(2 * (h1base + hh)) * NW + 4 * xq];
    }
  };
  auto ldswrite = [&]() {             // keep .x,.z of each stride-2 float4
    #pragma unroll
    for (int q = 0; q < 12; ++q) {
      const int idx = t + q * 256;
      const int xh = idx & 15;
      const int r  = (idx >> 4) % 12;
      const int c  = idx / 192;
      s2[c][r][2 * xh]     = R2[q].x;
      s2[c][r][2 * xh + 1] = R2[q].z;
    }
    #pragma unroll
    for (int q = 0; q < 3; ++q) {
      const int idx = t + q * 256;
      const int xq = idx % 12;
      const int hh = (idx / 12) & 3;
      const int c  = idx / 48;
      s1[c][hh][2 * xq]     = R1[q].x;
      s1[c][hh][2 * xq + 1] = R1[q].z;
    }
  };

  float acc[9][4];
  #pragma unroll
  for (int i = 0; i < 9; ++i) { acc[i][0]=0.f; acc[i][1]=0.f; acc[i][2]=0.f; acc[i][3]=0.f; }

  auto compute = [&]() {
    if (t >= NT) return;
    #pragma unroll 4
    for (int c = 0; c < CCH; ++c) {
      const float4 a4 = *(const float4*)&s1[c][h1l][wg * 4];
      const float* xr = &s2[c][h1l + j][wg * 4];
      const float4 b0 = *(const float4*)&xr[0];
      const float4 b1 = *(const float4*)&xr[4];
      const float4 b2 = *(const float4*)&xr[8];
      const float av[4]  = {a4.x, a4.y, a4.z, a4.w};
      const float xw[12] = {b0.x, b0.y, b0.z, b0.w, b1.x, b1.y, b1.z, b1.w,
                            b2.x, b2.y, b2.z, b2.w};
      #pragma unroll
      for (int i = 0; i < 9; ++i)
        #pragma unroll
        for (int w = 0; w < 4; ++w)
          acc[i][w] = fmaf(av[w], xw[w + i], acc[i][w]);
    }
  };

  // pipelined 2-chunk schedule: chunk-1 loads issue before chunk-0 compute
  loads(0);
  ldswrite();
  __syncthreads();
  loads(1);          // HBM latency hides under compute below
  compute();
  __syncthreads();   // all chunk-0 readers done before overwrite
  ldswrite();
  __syncthreads();
  compute();

  if (MODE == 0) {
    if (t >= NT) return;
    // transposed fp16 partials: wave store = 512 B contiguous per i
    const int tile = h1t * NB + b;
    Half4* pb = (Half4*)dst + ((size_t)cz * NTILE + tile) * PPT;
    #pragma unroll
    for (int i = 0; i < 9; ++i) {
      Half4 h;
      h.lo = __floats2half2_rn(acc[i][0], acc[i][1]);
      h.hi = __floats2half2_rn(acc[i][2], acc[i][3]);
      pb[i * NT + t] = h;
    }
  } else {
    if (t >= NT) return;
    float* out = (float*)dst;
    const int h1 = h1base + h1l;
    const int w1 = wg * 4;
    #pragma unroll
    for (int i = 0; i < 9; ++i) {
      const int k = j * 9 + i;
      #pragma unroll
      for (int w = 0; w < 4; ++w)
        atomicAdd(&out[((size_t)(b * NK + k) * H1 + h1) * W1 + w1 + w],
                  acc[i][w] * (1.f / 256.f));
    }
  }
}

// Coalesced reduce: consecutive threads read consecutive Half4s per cz slice.
__global__ __launch_bounds__(256) void corr_reduce(const Half4* __restrict__ part,
                                                   float* __restrict__ out)
{
  const int n = blockIdx.x * 256 + threadIdx.x;   // 0 .. 186623
  if (n >= OUTSZ / 4) return;
  const int tile = n / PPT;          // h1t*16 + b
  const int rem  = n % PPT;          // i*216 + tp
  const int i    = rem / NT;
  const int tp   = rem % NT;

  float4 s = make_float4(0.f, 0.f, 0.f, 0.f);
  #pragma unroll
  for (int cz = 0; cz < CSPLIT; ++cz) {
    const Half4 v = part[((size_t)cz * NTILE + tile) * PPT + rem];
    const float2 lo = __half22float2(v.lo);
    const float2 hi = __half22float2(v.hi);
    s.x += lo.x; s.y += lo.y; s.z += hi.x; s.w += hi.y;
  }
  const float sc = 1.f / (float)NC;
  const int b   = tile % NB;
  const int h1t = tile / NB;
  const int h1l = tp / 54;
  const int r2  = tp % 54;
  const int j   = r2 / 6;
  const int wg  = r2 % 6;
  const int k   = j * 9 + i;
  const int h1  = h1t * TH + h1l;
  *(float4*)&out[(((size_t)b * NK + k) * H1 + h1) * W1 + wg * 4] =
      make_float4(s.x * sc, s.y * sc, s.z * sc, s.w * sc);
}

extern "C" void kernel_launch(void* const* d_in, const int* in_sizes, int n_in,
                              void* d_out, int out_size, void* d_ws, size_t ws_size,
                              hipStream_t stream) {
  const float* x1 = (const float*)d_in[0];
  const float* x2 = (const float*)d_in[1];
  float* out = (float*)d_out;

  const size_t need = (size_t)CSPLIT * NTILE * PPT * sizeof(Half4);  // ~11.9 MB
  const dim3 grid(H1 / TH, NB, CSPLIT);   // (6, 16, 8) = 768 blocks
  if (ws_size >= need) {
    corr_main<0><<<grid, 256, 0, stream>>>(x1, x2, d_ws);
    corr_reduce<<<(OUTSZ / 4 + 255) / 256, 256, 0, stream>>>((const Half4*)d_ws, out);
  } else {
    hipMemsetAsync(d_out, 0, (size_t)OUTSZ * sizeof(float), stream);
    corr_main<1><<<grid, 256, 0, stream>>>(x1, x2, d_out);
  }
}